// Round 1
// 528.596 us; speedup vs baseline: 1.0329x; 1.0329x over previous
//
#include <hip/hip_runtime.h>

// out[n, f, h] = x[n, f] * W[f, h] + b[f, h]
// x: [16384, 128] f32, W/b: [128, 64] f32, out: [16384, 128, 64] f32.
//
// Write-BW-bound (512 MiB store). This version removes the LDS staging
// entirely: with flat float4 index idx = base + i*BLOCK (BLOCK=1024), the
// W/b index  wb = idx & 2047  only ever takes TWO values per thread
// (i*1024 mod 2048 ∈ {0,1024}).  So each thread hoists its two (w,b)
// float4 pairs into 16 VGPRs via coalesced global loads (W/b are 64 KB,
// L2-resident), and the 64-iteration loop body is just:
//     x-load -> 4 fma -> nontemporal 16B store.
// No LDS, no __syncthreads, no ds_read on the critical path.
//
// x loads are PLAIN (not nontemporal): each 64B x line is broadcast to 16
// lanes and reused by 4 consecutive waves -> let L1 serve it.
// Stores stay nontemporal: 512 MiB streamed once, zero reuse.

typedef float f4 __attribute__((ext_vector_type(4)));

#define BATCH 16384
#define NFEAT 128
#define H4 16
#define TOTAL_VEC4 (BATCH * NFEAT * H4)      // 33,554,432 float4
#define BLOCK 1024
#define GRID 512
#define ITERS (TOTAL_VEC4 / (BLOCK * GRID))  // 64

__global__ __launch_bounds__(BLOCK) void ifl_kernel(
    const float* __restrict__ x,
    const f4* __restrict__ W4,
    const f4* __restrict__ B4,
    f4* __restrict__ out) {
    const unsigned t = threadIdx.x;
    const unsigned base = blockIdx.x * (BLOCK * ITERS) + t;

    // The only two W/b entries this thread ever needs.
    const unsigned wb0 = base & (NFEAT * H4 - 1);          // parity-0 iters
    const unsigned wb1 = (base + BLOCK) & (NFEAT * H4 - 1); // parity-1 iters
    const f4 w0 = W4[wb0];
    const f4 b0 = B4[wb0];
    const f4 w1 = W4[wb1];
    const f4 b1 = B4[wb1];

#pragma unroll 8
    for (int i = 0; i < ITERS; i += 2) {
        const unsigned idx0 = base + i * BLOCK;
        const unsigned idx1 = idx0 + BLOCK;
        const float xv0 = x[idx0 >> 4];
        const float xv1 = x[idx1 >> 4];
        f4 o0, o1;
        o0.x = fmaf(xv0, w0.x, b0.x);
        o0.y = fmaf(xv0, w0.y, b0.y);
        o0.z = fmaf(xv0, w0.z, b0.z);
        o0.w = fmaf(xv0, w0.w, b0.w);
        o1.x = fmaf(xv1, w1.x, b1.x);
        o1.y = fmaf(xv1, w1.y, b1.y);
        o1.z = fmaf(xv1, w1.z, b1.z);
        o1.w = fmaf(xv1, w1.w, b1.w);
        __builtin_nontemporal_store(o0, &out[idx0]);
        __builtin_nontemporal_store(o1, &out[idx1]);
    }
}

extern "C" void kernel_launch(void* const* d_in, const int* in_sizes, int n_in,
                              void* d_out, int out_size, void* d_ws, size_t ws_size,
                              hipStream_t stream) {
    const float* x = (const float*)d_in[0];
    const f4* W4 = (const f4*)d_in[1];
    const f4* B4 = (const f4*)d_in[2];
    f4* out = (f4*)d_out;

    ifl_kernel<<<GRID, BLOCK, 0, stream>>>(x, W4, B4, out);
}